// Round 12
// baseline (69.328 us; speedup 1.0000x reference)
//
#include <hip/hip_runtime.h>
#include <hip/hip_bf16.h>

// kernel[i,j] = | prod_{k<16} cos((x[i,k]-y[j,k])/2) |   (f32 in, f32 out)
//
// MFMA formulation (verified r10/r11, absmax 0.0039): per wire-pair
//   cos(a)cos(b) = 1/2[cos(Rm-Cm) + cos(Rp-Cp)]  -> 4-term separable dot;
// a quad (pair x pair) is a 16-term dot  Q_q = sum_t A_q[i,t] B_q[j,t];
// out = |Q0 Q1 Q2 Q3|.
//
// r12 vs r11 (62.2 us): switch 16x16x32 (half-K zeroed) -> 32x32x16 (K=16
// exact). Operands SWAPPED: A-operand = column factors, B-operand = row
// factors, so D's reg dim = output COLUMN -> epilogue packs 4 consecutive
// cols into one NT global_store_dwordx4 (stores/lane 16 scalar -> 4 x16B).
// Frag b128 reads/wave drop 20 -> 8; MFMA/wave 16 -> 4.
// D layout (m74/m101): n = lane&31 (-> output row), m = (reg&3)+8*(reg>>2)
// +4*(lane>>5) (-> output col). A/B frag: elem dim = lane&31, k = (lane>>5)*8+j.

constexpr int D = 16;
constexpr int RSTR = 72;   // LDS row stride in shorts (144 B)

typedef short  bf16x8 __attribute__((ext_vector_type(8)));
typedef float  f32x16 __attribute__((ext_vector_type(16)));
typedef float  vf4    __attribute__((ext_vector_type(4)));

static __device__ inline unsigned int pk2(float a, float b) {
    __hip_bfloat16 ha = __float2bfloat16(a);
    __hip_bfloat16 hb = __float2bfloat16(b);
    unsigned short ua, ub;
    __builtin_memcpy(&ua, &ha, 2);
    __builtin_memcpy(&ub, &hb, 2);
    return (unsigned int)ua | ((unsigned int)ub << 16);
}

__global__ __launch_bounds__(256)
void qkern(const float* __restrict__ x, const float* __restrict__ y,
           float* __restrict__ out, int m) {
    __shared__ unsigned short Al[64 * RSTR];   // row terms: 64 rows x 64 bf16
    __shared__ unsigned short Bl[64 * RSTR];   // col terms: 64 cols x 64 bf16

    const int tid   = threadIdx.x;
    const int row0b = blockIdx.x * 64;
    const int col0b = blockIdx.y * 64;

    // ---- Stage (identical to r11): 128 units, 2 threads/unit. ----
    {
        const int u    = tid >> 1;
        const int half = tid & 1;
        const bool isrow = (u < 64);
        const float* src = isrow ? (x + (size_t)(row0b + u) * D)
                                 : (y + (size_t)(col0b + (u - 64)) * D);
        unsigned short* dst = (isrow ? Al + (size_t)u * RSTR
                                     : Bl + (size_t)(u - 64) * RSTR);
        const float scale = isrow ? 0.5f : 1.0f;

        float f[4][4];
#pragma unroll
        for (int pp = 0; pp < 4; ++pp) {
            const int p = half * 4 + pp;
            const float a0 = src[2 * p], a1 = src[2 * p + 1];
            float sm, cm, sp, cp;
            __sincosf(0.5f * (a0 - a1), &sm, &cm);
            __sincosf(0.5f * (a0 + a1), &sp, &cp);
            f[pp][0] = scale * cm; f[pp][1] = scale * sm;
            f[pp][2] = scale * cp; f[pp][3] = scale * sp;
        }
#pragma unroll
        for (int qq = 0; qq < 2; ++qq) {
            const int q = half * 2 + qq;
            const float* fa = f[2 * qq];
            const float* fb = f[2 * qq + 1];
            uint4 lo, hi;
            lo.x = pk2(fa[0] * fb[0], fa[0] * fb[1]);
            lo.y = pk2(fa[0] * fb[2], fa[0] * fb[3]);
            lo.z = pk2(fa[1] * fb[0], fa[1] * fb[1]);
            lo.w = pk2(fa[1] * fb[2], fa[1] * fb[3]);
            hi.x = pk2(fa[2] * fb[0], fa[2] * fb[1]);
            hi.y = pk2(fa[2] * fb[2], fa[2] * fb[3]);
            hi.z = pk2(fa[3] * fb[0], fa[3] * fb[1]);
            hi.w = pk2(fa[3] * fb[2], fa[3] * fb[3]);
            *(uint4*)(dst + q * 16)     = lo;
            *(uint4*)(dst + q * 16 + 8) = hi;
        }
    }
    __syncthreads();

    // ---- MFMA phase: each wave computes one 32x32 quadrant. ----
    const int wave = tid >> 6;
    const int lane = tid & 63;
    const int l31  = lane & 31;
    const int kh   = lane >> 5;          // k-half: 0 -> k0..7, 1 -> k8..15
    const int rw   = (wave >> 1) * 32;   // quadrant row base in tile
    const int cw   = (wave & 1) * 32;    // quadrant col base in tile

    const f32x16 zc = {0.f};

    // A-operand = COLUMN factors (m dim = output col), B = ROW factors.
    f32x16 prod;
    {
        const bf16x8 a0 = *(const bf16x8*)(Bl + (size_t)(cw + l31) * RSTR + 0 * 16 + kh * 8);
        const bf16x8 b0 = *(const bf16x8*)(Al + (size_t)(rw + l31) * RSTR + 0 * 16 + kh * 8);
        prod = __builtin_amdgcn_mfma_f32_32x32x16_bf16(a0, b0, zc, 0, 0, 0);
    }
#pragma unroll
    for (int q = 1; q < 4; ++q) {
        const bf16x8 aq = *(const bf16x8*)(Bl + (size_t)(cw + l31) * RSTR + q * 16 + kh * 8);
        const bf16x8 bq = *(const bf16x8*)(Al + (size_t)(rw + l31) * RSTR + q * 16 + kh * 8);
        const f32x16 acc = __builtin_amdgcn_mfma_f32_32x32x16_bf16(aq, bq, zc, 0, 0, 0);
        prod *= acc;     // elementwise; acc[q] dead after use (VGPR relief)
    }

    // Epilogue: D reg r -> output col = (r&3) + 8*(r>>2) + 4*kh; row = l31.
    const int orow = row0b + rw + l31;
    float* rowp = out + (size_t)orow * m + col0b + cw + 4 * kh;
#pragma unroll
    for (int g = 0; g < 4; ++g) {
        vf4 v;
        v.x = fabsf(prod[4 * g + 0]);
        v.y = fabsf(prod[4 * g + 1]);
        v.z = fabsf(prod[4 * g + 2]);
        v.w = fabsf(prod[4 * g + 3]);
        __builtin_nontemporal_store(v, (vf4*)(rowp + 8 * g));
    }
}

extern "C" void kernel_launch(void* const* d_in, const int* in_sizes, int n_in,
                              void* d_out, int out_size, void* d_ws, size_t ws_size,
                              hipStream_t stream) {
    const float* x = (const float*)d_in[0];
    const float* y = (const float*)d_in[1];
    float* out = (float*)d_out;
    const int n = in_sizes[0] / D;   // 2048
    const int m = in_sizes[1] / D;   // 2048

    dim3 grid(n / 64, m / 64);       // 32 x 32 = 1024 blocks -> 4 blk/CU
    qkern<<<grid, 256, 0, stream>>>(x, y, out, m);
}

// Round 13
// 60.592 us; speedup vs baseline: 1.1442x; 1.1442x over previous
//
#include <hip/hip_runtime.h>
#include <hip/hip_bf16.h>

// kernel[i,j] = | prod_{k<16} cos((x[i,k]-y[j,k])/2) |   (f32 in, f32 out)
//
// MFMA formulation (verified r10-r12, absmax 0.0039): per wire-pair
//   cos(a)cos(b) = 1/2[cos(Rm-Cm) + cos(Rp-Cp)]  -> 4-term separable dot;
// quad (pair x pair) = 16-term dot; out = |Q0 Q1 Q2 Q3|.
//
// r13 vs r11 (62.2) / r12 (69.3): 32x32x16 MFMA (K=16 exact, 4 MFMA + 8
// b128/wave vs r11's 16 + 20) with the PROPER orientation: A=row factors,
// B=col factors => D's LANE dim = output column (m74/m101; r12 validated the
// layout numerically). Store instructions therefore cover contiguous 128 B
// column segments (r12's swap put the col dim in the reg index -> 64-way
// 16 B scatter per store, +7 us. Lane dim MUST walk output columns.)

constexpr int D = 16;
constexpr int RSTR = 72;   // LDS row stride in shorts (144 B, 16B-aligned)

typedef short  bf16x8 __attribute__((ext_vector_type(8)));
typedef float  f32x16 __attribute__((ext_vector_type(16)));

static __device__ inline unsigned int pk2(float a, float b) {
    __hip_bfloat16 ha = __float2bfloat16(a);
    __hip_bfloat16 hb = __float2bfloat16(b);
    unsigned short ua, ub;
    __builtin_memcpy(&ua, &ha, 2);
    __builtin_memcpy(&ub, &hb, 2);
    return (unsigned int)ua | ((unsigned int)ub << 16);
}

__global__ __launch_bounds__(256)
void qkern(const float* __restrict__ x, const float* __restrict__ y,
           float* __restrict__ out, int m) {
    __shared__ unsigned short Al[64 * RSTR];   // row terms: 64 rows x 64 bf16
    __shared__ unsigned short Bl[64 * RSTR];   // col terms: 64 cols x 64 bf16

    const int tid   = threadIdx.x;
    const int row0b = blockIdx.x * 64;
    const int col0b = blockIdx.y * 64;

    // ---- Stage (identical to r11/r12): 128 units, 2 threads/unit. ----
    {
        const int u    = tid >> 1;
        const int half = tid & 1;
        const bool isrow = (u < 64);
        const float* src = isrow ? (x + (size_t)(row0b + u) * D)
                                 : (y + (size_t)(col0b + (u - 64)) * D);
        unsigned short* dst = (isrow ? Al + (size_t)u * RSTR
                                     : Bl + (size_t)(u - 64) * RSTR);
        const float scale = isrow ? 0.5f : 1.0f;

        float f[4][4];
#pragma unroll
        for (int pp = 0; pp < 4; ++pp) {
            const int p = half * 4 + pp;
            const float a0 = src[2 * p], a1 = src[2 * p + 1];
            float sm, cm, sp, cp;
            __sincosf(0.5f * (a0 - a1), &sm, &cm);
            __sincosf(0.5f * (a0 + a1), &sp, &cp);
            f[pp][0] = scale * cm; f[pp][1] = scale * sm;
            f[pp][2] = scale * cp; f[pp][3] = scale * sp;
        }
#pragma unroll
        for (int qq = 0; qq < 2; ++qq) {
            const int q = half * 2 + qq;
            const float* fa = f[2 * qq];
            const float* fb = f[2 * qq + 1];
            uint4 lo, hi;
            lo.x = pk2(fa[0] * fb[0], fa[0] * fb[1]);
            lo.y = pk2(fa[0] * fb[2], fa[0] * fb[3]);
            lo.z = pk2(fa[1] * fb[0], fa[1] * fb[1]);
            lo.w = pk2(fa[1] * fb[2], fa[1] * fb[3]);
            hi.x = pk2(fa[2] * fb[0], fa[2] * fb[1]);
            hi.y = pk2(fa[2] * fb[2], fa[2] * fb[3]);
            hi.z = pk2(fa[3] * fb[0], fa[3] * fb[1]);
            hi.w = pk2(fa[3] * fb[2], fa[3] * fb[3]);
            *(uint4*)(dst + q * 16)     = lo;
            *(uint4*)(dst + q * 16 + 8) = hi;
        }
    }
    __syncthreads();

    // ---- MFMA: wave = one 32x32 quadrant. A=rows, B=cols. ----
    const int wave = tid >> 6;
    const int lane = tid & 63;
    const int l31  = lane & 31;
    const int kh   = lane >> 5;          // k-half: 0 -> k0..7, 1 -> k8..15
    const int rw   = (wave >> 1) * 32;   // quadrant row base
    const int cw   = (wave & 1) * 32;    // quadrant col base

    const f32x16 zc = {0.f};

    f32x16 prod;
    {
        const bf16x8 a0 = *(const bf16x8*)(Al + (size_t)(rw + l31) * RSTR + 0 * 16 + kh * 8);
        const bf16x8 b0 = *(const bf16x8*)(Bl + (size_t)(cw + l31) * RSTR + 0 * 16 + kh * 8);
        prod = __builtin_amdgcn_mfma_f32_32x32x16_bf16(a0, b0, zc, 0, 0, 0);
    }
#pragma unroll
    for (int q = 1; q < 4; ++q) {
        const bf16x8 aq = *(const bf16x8*)(Al + (size_t)(rw + l31) * RSTR + q * 16 + kh * 8);
        const bf16x8 bq = *(const bf16x8*)(Bl + (size_t)(cw + l31) * RSTR + q * 16 + kh * 8);
        const f32x16 acc = __builtin_amdgcn_mfma_f32_32x32x16_bf16(aq, bq, zc, 0, 0, 0);
        prod *= acc;
    }

    // Epilogue: D reg r -> row = rw + (r&3) + 8*(r>>2) + 4*kh; col = cw+l31.
    // Lanes walk contiguous cols -> each store = 2 x 128 B full-line segments.
    const int ocol = col0b + cw + l31;
    float* base = out + (size_t)(row0b + rw + 4 * kh) * m + ocol;
#pragma unroll
    for (int r = 0; r < 16; ++r) {
        const int row_off = (r & 3) + 8 * (r >> 2);
        __builtin_nontemporal_store(fabsf(prod[r]), base + (size_t)row_off * m);
    }
}

extern "C" void kernel_launch(void* const* d_in, const int* in_sizes, int n_in,
                              void* d_out, int out_size, void* d_ws, size_t ws_size,
                              hipStream_t stream) {
    const float* x = (const float*)d_in[0];
    const float* y = (const float*)d_in[1];
    float* out = (float*)d_out;
    const int n = in_sizes[0] / D;   // 2048
    const int m = in_sizes[1] / D;   // 2048

    dim3 grid(n / 64, m / 64);       // 32 x 32 = 1024 blocks -> 4 blk/CU
    qkern<<<grid, 256, 0, stream>>>(x, y, out, m);
}